// Round 1
// baseline (272.516 us; speedup 1.0000x reference)
//
#include <hip/hip_runtime.h>

#define NN 2048   // factor dim
#define KK 16     // nonzeros per row

// ---------------------------------------------------------------------------
// Stage A: compose W0 @ W1 into per-column coefficient table.
// W01[c1][i] = coefficient of x[s1' + 128*i] in y1[c1], s1' = (c1-1) mod 128.
// y1[c1] = sum_k1 y0[r0]*v1[r0*16+k1], r0 = (c1-1-128*k1) mod N
// y0[r0] = sum_k0 x[rx]*v0[rx*16+k0],  rx = (r0-128*k0) mod N
// For target rx = s1' + 128*i:  k0 = (t1 - k1 - i) mod 16,  t1 = ((c1-1) mod N)>>7
// ---------------------------------------------------------------------------
__global__ __launch_bounds__(256) void sfd_compose01(const float* __restrict__ v0,
                                                     const float* __restrict__ v1,
                                                     float* __restrict__ w01) {
  int tid = blockIdx.x * 256 + threadIdx.x;   // 32768 threads: (c1, i)
  int c1 = tid >> 4;
  int i  = tid & 15;
  int cm = (c1 + NN - 1) & (NN - 1);          // (c1 - 1) mod N
  int s1 = cm & 127;
  int t1 = cm >> 7;
  int rx = s1 + (i << 7);
  float acc = 0.f;
#pragma unroll
  for (int k1 = 0; k1 < 16; ++k1) {
    int r0 = (cm - (k1 << 7)) & (NN - 1);
    int k0 = (t1 - k1 - i) & 15;
    acc = fmaf(v1[r0 * 16 + k1], v0[rx * 16 + k0], acc);
  }
  w01[c1 * 16 + i] = acc;
}

// ---------------------------------------------------------------------------
// Stage B: compose (W0@W1) @ W2, fold in scaling, store residue-major:
// mcl[((s*16 + j)*16) + i]  for col c = s + 128*j, coefficient of
// x[((c-3) mod 128) + 128*i].
// ---------------------------------------------------------------------------
__global__ __launch_bounds__(256) void sfd_compose012(const float* __restrict__ v2,
                                                      const float* __restrict__ w01,
                                                      const float* __restrict__ scaling,
                                                      float* __restrict__ mcl) {
  int tid = blockIdx.x * 256 + threadIdx.x;   // 32768 threads: (c, i)
  int c = tid >> 4;
  int i = tid & 15;
  float acc = 0.f;
#pragma unroll
  for (int k2 = 0; k2 < 16; ++k2) {
    int r1 = (c + NN - 2 - (k2 << 7)) & (NN - 1);
    acc = fmaf(v2[r1 * 16 + k2], w01[r1 * 16 + i], acc);
  }
  int s = c & 127;
  int j = c >> 7;
  mcl[(s * 16 + j) * 16 + i] = acc * scaling[0];
}

// ---------------------------------------------------------------------------
// Apply: out[b][c] = relu( sum_i mcl[c][i] * x[b][(c-3)%128 + 128*i] + bias[c] )
// Block: strip of 32 residues (512 cols) x 64 batch rows.
// Thread: (s_idx = t&31, jp = t>>5) -> 2 columns c = S0+s_idx+128*(2jp+{0,1}),
// coefficients (2x16 floats) held in registers across all 64 rows.
// x staged through LDS in 8-row chunks; xs[idx] layout = [r][i][u] (u = s_idx).
// ---------------------------------------------------------------------------
__global__ __launch_bounds__(256) void sfd_apply(const float* __restrict__ x,
                                                 const float* __restrict__ mcl,
                                                 const float* __restrict__ bias,
                                                 float* __restrict__ out) {
  const int S0 = blockIdx.x << 5;             // strip base residue: 0,32,64,96
  const int b0 = blockIdx.y << 6;             // first batch row of this block
  const int t = threadIdx.x;
  const int s_idx = t & 31;
  const int jp = t >> 5;                      // 0..7
  const int s = S0 + s_idx;                   // residue (= col mod 128)
  const int j0 = jp << 1;

  // Load this thread's 2x16 coefficients into registers (contiguous 128 B).
  float mc0[16], mc1[16];
  {
    const float4* p0 = (const float4*)(mcl + ((s * 16 + j0) << 4));
    const float4* p1 = (const float4*)(mcl + ((s * 16 + j0 + 1) << 4));
#pragma unroll
    for (int q = 0; q < 4; ++q) {
      float4 a = p0[q];
      mc0[4 * q + 0] = a.x; mc0[4 * q + 1] = a.y;
      mc0[4 * q + 2] = a.z; mc0[4 * q + 3] = a.w;
      float4 b = p1[q];
      mc1[4 * q + 0] = b.x; mc1[4 * q + 1] = b.y;
      mc1[4 * q + 2] = b.z; mc1[4 * q + 3] = b.w;
    }
  }
  const int c0 = s + (j0 << 7);
  const int c1 = c0 + 128;
  const float bi0 = bias[c0];
  const float bi1 = bias[c1];

  __shared__ float xs[8 * 512];               // 16 KiB: 8 rows x 512 cols

  for (int ch = 0; ch < 8; ++ch) {
    const int rb = b0 + (ch << 3);
    // ---- stage 8 rows x 512 needed cols, coalesced (128-B segments) ----
#pragma unroll
    for (int q = 0; q < 16; ++q) {
      int idx = t + (q << 8);                 // 0..4095 = r*512 + i*32 + u
      int u = idx & 31;
      int i = (idx >> 5) & 15;
      int r = idx >> 9;
      int col = ((S0 + 125 + u) & 127) + (i << 7);  // ((S0-3+u) mod 128) + 128*i
      xs[idx] = x[(size_t)(rb + r) * NN + col];
    }
    __syncthreads();
    // ---- compute 8 rows x 2 cols per thread ----
#pragma unroll 1
    for (int r = 0; r < 8; ++r) {
      const float* xr = xs + (r << 9) + s_idx;
      float acc0 = 0.f, acc1 = 0.f;
#pragma unroll
      for (int i = 0; i < 16; ++i) {
        float xv = xr[i << 5];                // conflict-free: stride-1 + broadcast
        acc0 = fmaf(xv, mc0[i], acc0);
        acc1 = fmaf(xv, mc1[i], acc1);
      }
      size_t ob = (size_t)(rb + r) * NN;
      out[ob + c0] = fmaxf(acc0 + bi0, 0.f);
      out[ob + c1] = fmaxf(acc1 + bi1, 0.f);
    }
    __syncthreads();
  }
}

extern "C" void kernel_launch(void* const* d_in, const int* in_sizes, int n_in,
                              void* d_out, int out_size, void* d_ws, size_t ws_size,
                              hipStream_t stream) {
  // setup_inputs order:
  // 0:x 1:vals0 2:vals1 3:vals2 4:rows0 5:cols0 6:rows1 7:cols1 8:rows2 9:cols2
  // 10:scaling 11:bias
  const float* x       = (const float*)d_in[0];
  const float* v0      = (const float*)d_in[1];
  const float* v1      = (const float*)d_in[2];
  const float* v2      = (const float*)d_in[3];
  const float* scaling = (const float*)d_in[10];
  const float* bias    = (const float*)d_in[11];
  float* out = (float*)d_out;

  float* w01 = (float*)d_ws;          // 2048*16 floats = 128 KiB
  float* mcl = w01 + NN * KK;         // 2048*16 floats = 128 KiB

  const int B = in_sizes[0] / NN;     // 16384

  hipLaunchKernelGGL(sfd_compose01, dim3(128), dim3(256), 0, stream, v0, v1, w01);
  hipLaunchKernelGGL(sfd_compose012, dim3(128), dim3(256), 0, stream, v2, w01, scaling, mcl);
  hipLaunchKernelGGL(sfd_apply, dim3(4, B >> 6), dim3(256), 0, stream, x, mcl, bias, out);
}

// Round 2
// 272.469 us; speedup vs baseline: 1.0002x; 1.0002x over previous
//
#include <hip/hip_runtime.h>

#define NN 2048   // factor dim
#define KK 16     // nonzeros per row

// ---------------------------------------------------------------------------
// Stage A: compose W0 @ W1 into per-column coefficient table.
// W01[c1][i] = coefficient of x[s1' + 128*i] in y1[c1], s1' = (c1-1) mod 128.
// ---------------------------------------------------------------------------
__global__ __launch_bounds__(256) void sfd_compose01(const float* __restrict__ v0,
                                                     const float* __restrict__ v1,
                                                     float* __restrict__ w01) {
  int tid = blockIdx.x * 256 + threadIdx.x;   // 32768 threads: (c1, i)
  int c1 = tid >> 4;
  int i  = tid & 15;
  int cm = (c1 + NN - 1) & (NN - 1);          // (c1 - 1) mod N
  int s1 = cm & 127;
  int t1 = cm >> 7;
  int rx = s1 + (i << 7);
  float acc = 0.f;
#pragma unroll
  for (int k1 = 0; k1 < 16; ++k1) {
    int r0 = (cm - (k1 << 7)) & (NN - 1);
    int k0 = (t1 - k1 - i) & 15;
    acc = fmaf(v1[r0 * 16 + k1], v0[rx * 16 + k0], acc);
  }
  w01[c1 * 16 + i] = acc;
}

// ---------------------------------------------------------------------------
// Stage B: compose (W0@W1) @ W2, fold in scaling, store residue-major:
// mcl[((s*16 + j)*16) + i]  for col c = s + 128*j, coefficient of
// x[((c-3) mod 128) + 128*i].
// ---------------------------------------------------------------------------
__global__ __launch_bounds__(256) void sfd_compose012(const float* __restrict__ v2,
                                                      const float* __restrict__ w01,
                                                      const float* __restrict__ scaling,
                                                      float* __restrict__ mcl) {
  int tid = blockIdx.x * 256 + threadIdx.x;   // 32768 threads: (c, i)
  int c = tid >> 4;
  int i = tid & 15;
  float acc = 0.f;
#pragma unroll
  for (int k2 = 0; k2 < 16; ++k2) {
    int r1 = (c + NN - 2 - (k2 << 7)) & (NN - 1);
    acc = fmaf(v2[r1 * 16 + k2], w01[r1 * 16 + i], acc);
  }
  int s = c & 127;
  int j = c >> 7;
  mcl[(s * 16 + j) * 16 + i] = acc * scaling[0];
}

// ---------------------------------------------------------------------------
// Apply: out[b][c] = relu( sum_i mcl[c][i] * x[b][(c-3)%128 + 128*i] + bias[c] )
// Block: strip of 32 residues (512 cols) x 32 batch rows; grid (4, 512) =
// 2048 blocks = 8 blocks/CU.  Thread (u=t&31, jp=t>>5) -> 2 cols
// c = S0+u+128*(2jp+{0,1}); 2x16 coefficients in registers (rotated by
// `shift` to absorb the mod-128 wrap so LDS slots are i-aligned).
// LDS layout xs[r][u][i] stride 20 floats: 16-B aligned -> ds_read_b128,
// odd*4 stride keeps b128 phase/bank density identical to contiguous.
// ---------------------------------------------------------------------------
__global__ __launch_bounds__(256, 8) void sfd_apply(const float* __restrict__ x,
                                                    const float* __restrict__ mcl,
                                                    const float* __restrict__ bias,
                                                    float* __restrict__ out) {
  const int S0 = blockIdx.x << 5;             // strip base residue: 0,32,64,96
  const int b0 = blockIdx.y << 5;             // 32 batch rows per block
  const int t = threadIdx.x;
  const int u = t & 31;
  const int jp = t >> 5;                      // 0..7
  const int s = S0 + u;                       // residue (= col mod 128), < 128
  const int j0 = jp << 1;
  const int w0 = (S0 + 125) & 127;            // (S0 - 3) mod 128
  const int shift = (w0 + u) >> 7;            // 1 iff this thread's window wraps

  // 2x16 coefficients into registers, rotated by `shift`:
  // LDS slot i holds x[(s-3)%128 + 128*((i+shift)&15)].
  float mc0[16], mc1[16];
  {
    const float* r0p = mcl + ((s * 16 + j0) << 4);
#pragma unroll
    for (int i = 0; i < 16; ++i) {
      int ic = (i + shift) & 15;
      mc0[i] = r0p[ic];
      mc1[i] = r0p[16 + ic];
    }
  }
  const int c0 = s + (j0 << 7);
  const int c1 = c0 + 128;
  const float bi0 = bias[c0];
  const float bi1 = bias[c1];

  __shared__ float xs[8 * 32 * 20];           // 20480 B: 8 rows x 32 u x stride 20

  for (int ch = 0; ch < 4; ++ch) {
    const int rb = b0 + (ch << 3);
    // ---- stage 8 rows x (32 residues x 16 i): 16 coalesced scalar global
    //      loads + 4 ds_write_b128 per thread ----
#pragma unroll
    for (int q = 0; q < 4; ++q) {
      int idx = t + (q << 8);                 // 0..1023 = rr*128 + ig*32 + uu
      int uu = idx & 31;
      int ig = (idx >> 5) & 3;                // i-group (4 i's)
      int rr = idx >> 7;                      // 0..7
      const float* xrow = x + (size_t)(rb + rr) * NN;
      int cb = w0 + uu + (ig << 9);           // w0+uu+128*(4*ig)
      float4 v;
      v.x = xrow[cb & (NN - 1)];
      v.y = xrow[(cb + 128) & (NN - 1)];
      v.z = xrow[(cb + 256) & (NN - 1)];
      v.w = xrow[(cb + 384) & (NN - 1)];
      *(float4*)(xs + (rr * 32 + uu) * 20 + (ig << 2)) = v;
    }
    __syncthreads();
    // ---- compute 8 rows x 2 cols per thread: 4 ds_read_b128 + 32 FMA ----
#pragma unroll 1
    for (int r = 0; r < 8; ++r) {
      const float4* xr = (const float4*)(xs + (r * 32 + u) * 20);
      float xv[16];
      *(float4*)(xv + 0)  = xr[0];
      *(float4*)(xv + 4)  = xr[1];
      *(float4*)(xv + 8)  = xr[2];
      *(float4*)(xv + 12) = xr[3];
      float acc0 = bi0, acc1 = bi1;
#pragma unroll
      for (int i = 0; i < 16; ++i) {
        acc0 = fmaf(xv[i], mc0[i], acc0);
        acc1 = fmaf(xv[i], mc1[i], acc1);
      }
      size_t ob = (size_t)(rb + r) * NN;
      __builtin_nontemporal_store(fmaxf(acc0, 0.f), &out[ob + c0]);
      __builtin_nontemporal_store(fmaxf(acc1, 0.f), &out[ob + c1]);
    }
    __syncthreads();
  }
}

extern "C" void kernel_launch(void* const* d_in, const int* in_sizes, int n_in,
                              void* d_out, int out_size, void* d_ws, size_t ws_size,
                              hipStream_t stream) {
  // 0:x 1:vals0 2:vals1 3:vals2 4:rows0 5:cols0 6:rows1 7:cols1 8:rows2 9:cols2
  // 10:scaling 11:bias
  const float* x       = (const float*)d_in[0];
  const float* v0      = (const float*)d_in[1];
  const float* v1      = (const float*)d_in[2];
  const float* v2      = (const float*)d_in[3];
  const float* scaling = (const float*)d_in[10];
  const float* bias    = (const float*)d_in[11];
  float* out = (float*)d_out;

  float* w01 = (float*)d_ws;          // 2048*16 floats = 128 KiB
  float* mcl = w01 + NN * KK;         // 2048*16 floats = 128 KiB

  const int B = in_sizes[0] / NN;     // 16384

  hipLaunchKernelGGL(sfd_compose01, dim3(128), dim3(256), 0, stream, v0, v1, w01);
  hipLaunchKernelGGL(sfd_compose012, dim3(128), dim3(256), 0, stream, v2, w01, scaling, mcl);
  hipLaunchKernelGGL(sfd_apply, dim3(4, B >> 5), dim3(256), 0, stream, x, mcl, bias, out);
}